// Round 19
// baseline (129.678 us; speedup 1.0000x reference)
//
#include <hip/hip_runtime.h>
#include <hip/hip_bf16.h>

typedef _Float16 f16;
typedef _Float16 f16x2 __attribute__((ext_vector_type(2)));
typedef _Float16 f16x4 __attribute__((ext_vector_type(4)));
typedef _Float16 f16x8 __attribute__((ext_vector_type(8)));
typedef __fp16 h16x2 __attribute__((ext_vector_type(2)));
typedef float f32x4 __attribute__((ext_vector_type(4)));

// Problem constants
#define NHEADS 6
#define NTOK 256
#define NWINS 256
#define DIM 192
#define HD 32
#define C3 576
#define LOG2E 1.4426950408889634f
#define SCALE (0.17677669529663687f * LOG2E)

__device__ inline f16x2 pkrtz(float a, float b) {
  h16x2 r = __builtin_amdgcn_cvt_pkrtz(a, b);
  return __builtin_bit_cast(f16x2, r);
}

// ---------------------------------------------------------------------------
// Kernel 1 (fused prep): blocks [0,3072) build cb16 (frag-major, vectorized);
// blocks [3072, 3090) convert W fp32->f16.
//   cb16[grp][q][ktp][g][e], grp = mg*6+h; element (q,k),
//   k = (2*ktp + (e>>2))*16 + g*4 + (e&3)
// ---------------------------------------------------------------------------
__global__ __launch_bounds__(256) void prep_kernel(const int* __restrict__ rpi,
                                                   const float* __restrict__ mask,
                                                   const float* __restrict__ rpb,
                                                   const float* __restrict__ w,
                                                   f16* __restrict__ cb,
                                                   f16* __restrict__ w16) {
  if (blockIdx.x >= 3072) {
    int u = (blockIdx.x - 3072) * 256 + threadIdx.x;
    if (u < 4608) {
      const float* wp = w + u * 8;
      float4 v0 = *(const float4*)wp;
      float4 v1 = *(const float4*)(wp + 4);
      f16x2 a = pkrtz(v0.x, v0.y);
      f16x2 b = pkrtz(v0.z, v0.w);
      f16x2 c = pkrtz(v1.x, v1.y);
      f16x2 d = pkrtz(v1.z, v1.w);
      f16x4 lo = __builtin_shufflevector(a, b, 0, 1, 2, 3);
      f16x4 hi = __builtin_shufflevector(c, d, 0, 1, 2, 3);
      *((f16x8*)(w16 + (size_t)u * 8)) =
          __builtin_shufflevector(lo, hi, 0, 1, 2, 3, 4, 5, 6, 7);
    }
    return;
  }
  int u = blockIdx.x * 256 + threadIdx.x;
  int g = u & 3;
  int ktp = (u >> 2) & 7;
  int q = (u >> 5) & 255;
  int grp = u >> 13;           // mg*6 + h
  int h = grp % 6;
  int mg = grp / 6;
  int k0 = ktp * 32 + g * 4;
  const int* rp = rpi + (q << 8) + k0;
  int4 i0 = *(const int4*)rp;
  int4 i1 = *(const int4*)(rp + 16);
  const float* mp = mask + ((size_t)mg << 16) + (q << 8) + k0;
  float4 mv0 = *(const float4*)mp;
  float4 mv1 = *(const float4*)(mp + 16);
  f16x2 a = pkrtz((rpb[i0.x * 6 + h] + mv0.x) * LOG2E,
                  (rpb[i0.y * 6 + h] + mv0.y) * LOG2E);
  f16x2 b = pkrtz((rpb[i0.z * 6 + h] + mv0.z) * LOG2E,
                  (rpb[i0.w * 6 + h] + mv0.w) * LOG2E);
  f16x2 c = pkrtz((rpb[i1.x * 6 + h] + mv1.x) * LOG2E,
                  (rpb[i1.y * 6 + h] + mv1.y) * LOG2E);
  f16x2 d = pkrtz((rpb[i1.z * 6 + h] + mv1.z) * LOG2E,
                  (rpb[i1.w * 6 + h] + mv1.w) * LOG2E);
  f16x4 lo = __builtin_shufflevector(a, b, 0, 1, 2, 3);
  f16x4 hi = __builtin_shufflevector(c, d, 0, 1, 2, 3);
  *((f16x8*)(cb + (size_t)u * 8)) =
      __builtin_shufflevector(lo, hi, 0, 1, 2, 3, 4, 5, 6, 7);
}

__device__ inline f16x8 q_to_f16(float4 a, float4 b) {
  f16x2 p0 = pkrtz(a.x * SCALE, a.y * SCALE);
  f16x2 p1 = pkrtz(a.z * SCALE, a.w * SCALE);
  f16x2 p2 = pkrtz(b.x * SCALE, b.y * SCALE);
  f16x2 p3 = pkrtz(b.z * SCALE, b.w * SCALE);
  f16x4 lo = __builtin_shufflevector(p0, p1, 0, 1, 2, 3);
  f16x4 hi = __builtin_shufflevector(p2, p3, 0, 1, 2, 3);
  return __builtin_shufflevector(lo, hi, 0, 1, 2, 3, 4, 5, 6, 7);
}

// ---------------------------------------------------------------------------
// Kernel 3: fused window attention — r19 QUADS.
// Grid 384 = 96 grps x 4; block processes 4 b's: b = ((pr*4+ib)<<4)|blo.
// All 384 blocks co-resident (512-block capacity at 2/CU) -> no launch-wave
// tail; 3 of 4 K/V stages fully overlapped with compute (vs 1 of 2 in r14's
// pairs) -> staging loads spread across the kernel lifetime (attacks the
// ~1.1 TB/s memory-concurrency limit). Buffer reuse safe: barrier at each
// b-boundary means buf[(i+1)%2]'s previous reader (b_{i-1}) has finished.
// Else r14 core: f16 frag-major cb seeds MFMA C, XCD pinning, (512,4),
// max-based online softmax over 2 k-halves, PV dual chains.
// ---------------------------------------------------------------------------
__global__ __launch_bounds__(512, 4) void attn_kernel(const float* __restrict__ qkv,
                                                      const f16* __restrict__ cb,
                                                      f16* __restrict__ x16) {
  const int idx = blockIdx.x;
  const int grp = idx % 96;            // (b&15)*6 + h — pinned to XCD grp%8
  const int pr = idx / 96;             // 0..3
  const int h = grp % 6;
  const int blo = grp / 6;             // b & 15
  const int tid = threadIdx.x;
  const int lane = tid & 63;
  const int wave = tid >> 6;
  const int g = lane >> 4;
  const int r16 = lane & 15;

  __shared__ f16 Klin[2][16 * 64 * 8];
  __shared__ f16 VT[2][32][264];

  // staging role
  const int t = tid & 255;
  const int srow = t >> 3;
  const int part = t & 7;
  const bool isK = tid < 256;
  const int gg = part >> 1;
  const int half = part & 1;
  const int d0 = part * 4;

  // per-thread staging base for window b: sb(b) = qkv + off
  const size_t soff = (size_t)srow * C3 + DIM + (isK ? 0 : DIM) + h * HD + part * 4;

  auto stage_write = [&](int buf, int rgbase, const float4* v4) {
#pragma unroll
    for (int rg = 0; rg < 4; ++rg) {
      const int row = (rgbase + rg) * 32 + srow;
      if (isK) {
        const int slot = ((row >> 4) * 64) + gg * 16 + ((row & 15) ^ (gg << 2));
        f16x2 k01 = pkrtz(v4[rg].x, v4[rg].y);
        f16x2 k23 = pkrtz(v4[rg].z, v4[rg].w);
        *((f16x4*)&Klin[buf][slot * 8 + half * 4]) =
            __builtin_shufflevector(k01, k23, 0, 1, 2, 3);
      } else {
        VT[buf][d0 + 0][row ^ (((d0 + 0) & 7) << 2)] = (f16)v4[rg].x;
        VT[buf][d0 + 1][row ^ (((d0 + 1) & 7) << 2)] = (f16)v4[rg].y;
        VT[buf][d0 + 2][row ^ (((d0 + 2) & 7) << 2)] = (f16)v4[rg].z;
        VT[buf][d0 + 3][row ^ (((d0 + 3) & 7) << 2)] = (f16)v4[rg].w;
      }
    }
  };

  // ---- ib=0: full stage into buffer 0 ----
  {
    const int b0 = ((pr * 4) << 4) | blo;
    const float* sb = qkv + (size_t)(b0 * NTOK) * C3 + soff;
    float4 s4[8];
#pragma unroll
    for (int i = 0; i < 8; ++i)
      s4[i] = *(const float4*)(sb + (size_t)(i * 32) * C3);
    stage_write(0, 0, s4);
    stage_write(0, 4, s4 + 4);
  }
  __syncthreads();

  const f16* cbb = cb + ((size_t)grp << 16);
  const int krd = (lane & 48) + ((lane & 15) ^ ((lane >> 2) & 12));
  const int qbase = wave * 32;

#pragma unroll
  for (int ib = 0; ib < 4; ++ib) {
    const int b = ((pr * 4 + ib) << 4) | blo;
    const int buf = ib & 1;
    const float* snext = qkv + (size_t)((b + 16) * NTOK) * C3 + soff;

#pragma unroll
    for (int c = 0; c < 2; ++c) {
      // issue next window's staging loads (batch c)
      float4 n4[4];
      if (ib < 3) {
#pragma unroll
        for (int i = 0; i < 4; ++i)
          n4[i] = *(const float4*)(snext + (size_t)((c * 4 + i) * 32) * C3);
      }

      const int qrow = qbase + c * 16 + r16;
      const float* qp = qkv + (size_t)(b * NTOK + qrow) * C3 + h * HD + g * 8;
      f16x8 qf = q_to_f16(((const float4*)qp)[0], ((const float4*)qp)[1]);
      const f16* cbq = cbb + (qrow << 8) + g * 8;

      // ================= phase A: keys 0..127 =================
      f16x8 cv[4];
#pragma unroll
      for (int kp = 0; kp < 4; ++kp) cv[kp] = *((const f16x8*)(cbq + kp * 32));
      f32x4 acc[8];
#pragma unroll
      for (int kp = 0; kp < 4; ++kp) {
#pragma unroll
        for (int r = 0; r < 4; ++r) {
          acc[2 * kp][r] = (float)cv[kp][r];
          acc[2 * kp + 1][r] = (float)cv[kp][4 + r];
        }
      }
#pragma unroll
      for (int kt = 0; kt < 8; ++kt) {
        f16x8 af = *((const f16x8*)&Klin[buf][(kt * 64 + krd) * 8]);
        acc[kt] = __builtin_amdgcn_mfma_f32_16x16x32_f16(af, qf, acc[kt], 0, 0, 0);
      }

      // write next window's staging batch (loads have had QK latency)
      if (ib < 3) stage_write(buf ^ 1, c * 4, n4);

      float m0 = fmaxf(fmaxf(acc[0][0], acc[1][0]), fmaxf(acc[2][0], acc[3][0]));
      float m1 = fmaxf(fmaxf(acc[0][1], acc[1][1]), fmaxf(acc[2][1], acc[3][1]));
      float m2 = fmaxf(fmaxf(acc[0][2], acc[1][2]), fmaxf(acc[2][2], acc[3][2]));
      float m3 = fmaxf(fmaxf(acc[0][3], acc[1][3]), fmaxf(acc[2][3], acc[3][3]));
#pragma unroll
      for (int kt = 4; kt < 8; ++kt) {
        m0 = fmaxf(m0, acc[kt][0]); m1 = fmaxf(m1, acc[kt][1]);
        m2 = fmaxf(m2, acc[kt][2]); m3 = fmaxf(m3, acc[kt][3]);
      }
      float mA = fmaxf(fmaxf(m0, m1), fmaxf(m2, m3));
      mA = fmaxf(mA, __shfl_xor(mA, 16));
      mA = fmaxf(mA, __shfl_xor(mA, 32));

      float s0 = 0.f, s1 = 0.f, s2 = 0.f, s3 = 0.f;
#pragma unroll
      for (int kt = 0; kt < 8; ++kt) {
        float p0 = __builtin_amdgcn_exp2f(acc[kt][0] - mA);
        float p1 = __builtin_amdgcn_exp2f(acc[kt][1] - mA);
        float p2 = __builtin_amdgcn_exp2f(acc[kt][2] - mA);
        float p3 = __builtin_amdgcn_exp2f(acc[kt][3] - mA);
        acc[kt][0] = p0; acc[kt][1] = p1; acc[kt][2] = p2; acc[kt][3] = p3;
        s0 += p0; s1 += p1; s2 += p2; s3 += p3;
      }
      float sA = (s0 + s1) + (s2 + s3);

      // PV phase A — 2 chains per dt
      f32x4 xa0[2], xa1[2];
#pragma unroll
      for (int dt = 0; dt < 2; ++dt) {
        xa0[dt][0] = 0.f; xa0[dt][1] = 0.f; xa0[dt][2] = 0.f; xa0[dt][3] = 0.f;
        xa1[dt][0] = 0.f; xa1[dt][1] = 0.f; xa1[dt][2] = 0.f; xa1[dt][3] = 0.f;
      }
#pragma unroll
      for (int kt = 0; kt < 8; ++kt) {
        f16x2 p01 = pkrtz(acc[kt][0], acc[kt][1]);
        f16x2 p23 = pkrtz(acc[kt][2], acc[kt][3]);
        f16x4 pf = __builtin_shufflevector(p01, p23, 0, 1, 2, 3);
#pragma unroll
        for (int dt = 0; dt < 2; ++dt) {
          const int col = (kt * 16 + g * 4) ^ ((r16 & 7) << 2);
          f16x4 vf = *((const f16x4*)&VT[buf][dt * 16 + r16][col]);
          if (kt < 4)
            xa0[dt] = __builtin_amdgcn_mfma_f32_16x16x16f16(vf, pf, xa0[dt], 0, 0, 0);
          else
            xa1[dt] = __builtin_amdgcn_mfma_f32_16x16x16f16(vf, pf, xa1[dt], 0, 0, 0);
        }
      }

      // ================= phase B: keys 128..255 =================
#pragma unroll
      for (int kp = 0; kp < 4; ++kp) cv[kp] = *((const f16x8*)(cbq + 128 + kp * 32));
#pragma unroll
      for (int kp = 0; kp < 4; ++kp) {
#pragma unroll
        for (int r = 0; r < 4; ++r) {
          acc[2 * kp][r] = (float)cv[kp][r];
          acc[2 * kp + 1][r] = (float)cv[kp][4 + r];
        }
      }
#pragma unroll
      for (int kt = 0; kt < 8; ++kt) {
        f16x8 af = *((const f16x8*)&Klin[buf][((kt + 8) * 64 + krd) * 8]);
        acc[kt] = __builtin_amdgcn_mfma_f32_16x16x32_f16(af, qf, acc[kt], 0, 0, 0);
      }

      m0 = fmaxf(fmaxf(acc[0][0], acc[1][0]), fmaxf(acc[2][0], acc[3][0]));
      m1 = fmaxf(fmaxf(acc[0][1], acc[1][1]), fmaxf(acc[2][1], acc[3][1]));
      m2 = fmaxf(fmaxf(acc[0][2], acc[1][2]), fmaxf(acc[2][2], acc[3][2]));
      m3 = fmaxf(fmaxf(acc[0][3], acc[1][3]), fmaxf(acc[2][3], acc[3][3]));
#pragma unroll
      for (int kt = 4; kt < 8; ++kt) {
        m0 = fmaxf(m0, acc[kt][0]); m1 = fmaxf(m1, acc[kt][1]);
        m2 = fmaxf(m2, acc[kt][2]); m3 = fmaxf(m3, acc[kt][3]);
      }
      float mB = fmaxf(fmaxf(m0, m1), fmaxf(m2, m3));
      mB = fmaxf(mB, __shfl_xor(mB, 16));
      mB = fmaxf(mB, __shfl_xor(mB, 32));

      const float m = fmaxf(mA, mB);
      const float scA = __builtin_amdgcn_exp2f(mA - m);

      s0 = 0.f; s1 = 0.f; s2 = 0.f; s3 = 0.f;
#pragma unroll
      for (int kt = 0; kt < 8; ++kt) {
        float p0 = __builtin_amdgcn_exp2f(acc[kt][0] - m);
        float p1 = __builtin_amdgcn_exp2f(acc[kt][1] - m);
        float p2 = __builtin_amdgcn_exp2f(acc[kt][2] - m);
        float p3 = __builtin_amdgcn_exp2f(acc[kt][3] - m);
        acc[kt][0] = p0; acc[kt][1] = p1; acc[kt][2] = p2; acc[kt][3] = p3;
        s0 += p0; s1 += p1; s2 += p2; s3 += p3;
      }
      float s = sA * scA + (s0 + s1) + (s2 + s3);
      s += __shfl_xor(s, 16);
      s += __shfl_xor(s, 32);
      const float rinv = 1.0f / s;

#pragma unroll
      for (int dt = 0; dt < 2; ++dt) {
        xa0[dt][0] *= scA; xa0[dt][1] *= scA; xa0[dt][2] *= scA; xa0[dt][3] *= scA;
        xa1[dt][0] *= scA; xa1[dt][1] *= scA; xa1[dt][2] *= scA; xa1[dt][3] *= scA;
      }
#pragma unroll
      for (int kt = 0; kt < 8; ++kt) {
        f16x2 p01 = pkrtz(acc[kt][0], acc[kt][1]);
        f16x2 p23 = pkrtz(acc[kt][2], acc[kt][3]);
        f16x4 pf = __builtin_shufflevector(p01, p23, 0, 1, 2, 3);
#pragma unroll
        for (int dt = 0; dt < 2; ++dt) {
          const int col = ((kt + 8) * 16 + g * 4) ^ ((r16 & 7) << 2);
          f16x4 vf = *((const f16x4*)&VT[buf][dt * 16 + r16][col]);
          if (kt < 4)
            xa0[dt] = __builtin_amdgcn_mfma_f32_16x16x16f16(vf, pf, xa0[dt], 0, 0, 0);
          else
            xa1[dt] = __builtin_amdgcn_mfma_f32_16x16x16f16(vf, pf, xa1[dt], 0, 0, 0);
        }
      }

      // write x (f16) [b][token][192], normalized
      f16* xp = x16 + (size_t)(b * NTOK + qrow) * DIM + h * HD;
#pragma unroll
      for (int dt = 0; dt < 2; ++dt) {
        f16x2 o01 = pkrtz((xa0[dt][0] + xa1[dt][0]) * rinv,
                          (xa0[dt][1] + xa1[dt][1]) * rinv);
        f16x2 o23 = pkrtz((xa0[dt][2] + xa1[dt][2]) * rinv,
                          (xa0[dt][3] + xa1[dt][3]) * rinv);
        *((f16x4*)(xp + dt * 16 + g * 4)) = __builtin_shufflevector(o01, o23, 0, 1, 2, 3);
      }
    }

    // b boundary: next buffer's staging writes must be visible
    if (ib < 3) __syncthreads();
  }
}

// ---------------------------------------------------------------------------
// Kernel 4: out = X16 @ W16^T + pb
// ---------------------------------------------------------------------------
__global__ __launch_bounds__(256) void proj_kernel(const f16* __restrict__ x16,
                                                   const f16* __restrict__ w16,
                                                   const float* __restrict__ pb,
                                                   float* __restrict__ out) {
  const int lane = threadIdx.x & 63;
  const int wave = threadIdx.x >> 6;
  const int g = lane >> 4;
  const int r16 = lane & 15;
  const int m0 = blockIdx.x * 64 + wave * 16;

  f32x4 acc[12];
#pragma unroll
  for (int jt = 0; jt < 12; ++jt) {
    acc[jt][0] = 0.f; acc[jt][1] = 0.f; acc[jt][2] = 0.f; acc[jt][3] = 0.f;
  }
#pragma unroll
  for (int cc = 0; cc < 6; ++cc) {
    f16x8 af = *((const f16x8*)(x16 + (size_t)(m0 + r16) * DIM + cc * 32 + g * 8));
#pragma unroll
    for (int jt = 0; jt < 12; ++jt) {
      f16x8 bf = *((const f16x8*)(w16 + (size_t)(jt * 16 + r16) * DIM + cc * 32 + g * 8));
      acc[jt] = __builtin_amdgcn_mfma_f32_16x16x32_f16(af, bf, acc[jt], 0, 0, 0);
    }
  }
#pragma unroll
  for (int jt = 0; jt < 12; ++jt) {
    int j = jt * 16 + r16;
    float bias = pb[j];
#pragma unroll
    for (int r = 0; r < 4; ++r) {
      out[(size_t)(m0 + g * 4 + r) * DIM + j] = acc[jt][r] + bias;
    }
  }
}

// ---------------------------------------------------------------------------
extern "C" void kernel_launch(void* const* d_in, const int* in_sizes, int n_in,
                              void* d_out, int out_size, void* d_ws, size_t ws_size,
                              hipStream_t stream) {
  const float* qkv  = (const float*)d_in[0];
  const int*   rpi  = (const int*)d_in[1];
  const float* mask = (const float*)d_in[2];
  const float* rpb  = (const float*)d_in[3];
  const float* pw   = (const float*)d_in[4];
  const float* pbv  = (const float*)d_in[5];
  float* out = (float*)d_out;

  char* ws = (char*)d_ws;
  f16* cb16 = (f16*)ws;                              // 12,582,912 B
  f16* x16  = (f16*)(ws + 12582912);                 // 25,165,824 B
  f16* w16  = (f16*)(ws + 12582912 + 25165824);      // 73,728 B

  prep_kernel<<<3090, 256, 0, stream>>>(rpi, mask, rpb, pw, cb16, w16);
  attn_kernel<<<384, 512, 0, stream>>>(qkv, cb16, x16);
  proj_kernel<<<1024, 256, 0, stream>>>(x16, w16, pbv, out);
}

// Round 20
// 107.748 us; speedup vs baseline: 1.2035x; 1.2035x over previous
//
#include <hip/hip_runtime.h>
#include <hip/hip_bf16.h>

typedef _Float16 f16;
typedef _Float16 f16x2 __attribute__((ext_vector_type(2)));
typedef _Float16 f16x4 __attribute__((ext_vector_type(4)));
typedef _Float16 f16x8 __attribute__((ext_vector_type(8)));
typedef __fp16 h16x2 __attribute__((ext_vector_type(2)));
typedef float f32x4 __attribute__((ext_vector_type(4)));

// Problem constants
#define NHEADS 6
#define NTOK 256
#define NWINS 256
#define DIM 192
#define HD 32
#define C3 576
#define LOG2E 1.4426950408889634f
#define SCALE (0.17677669529663687f * LOG2E)

__device__ inline f16x2 pkrtz(float a, float b) {
  h16x2 r = __builtin_amdgcn_cvt_pkrtz(a, b);
  return __builtin_bit_cast(f16x2, r);
}

// ---------------------------------------------------------------------------
// Kernel 1 (fused prep): blocks [0,3072) build cb16 (frag-major, vectorized);
// blocks [3072, 3090) convert W fp32->f16 (36864 elems, f16x8 each).
//   cb16[grp][q][ktp][g][e], grp = mg*6+h; element (q,k),
//   k = (2*ktp + (e>>2))*16 + g*4 + (e&3)
// ---------------------------------------------------------------------------
__global__ __launch_bounds__(256) void prep_kernel(const int* __restrict__ rpi,
                                                   const float* __restrict__ mask,
                                                   const float* __restrict__ rpb,
                                                   const float* __restrict__ w,
                                                   f16* __restrict__ cb,
                                                   f16* __restrict__ w16) {
  if (blockIdx.x >= 3072) {
    int u = (blockIdx.x - 3072) * 256 + threadIdx.x;
    if (u < 4608) {
      const float* wp = w + u * 8;
      float4 v0 = *(const float4*)wp;
      float4 v1 = *(const float4*)(wp + 4);
      f16x2 a = pkrtz(v0.x, v0.y);
      f16x2 b = pkrtz(v0.z, v0.w);
      f16x2 c = pkrtz(v1.x, v1.y);
      f16x2 d = pkrtz(v1.z, v1.w);
      f16x4 lo = __builtin_shufflevector(a, b, 0, 1, 2, 3);
      f16x4 hi = __builtin_shufflevector(c, d, 0, 1, 2, 3);
      *((f16x8*)(w16 + (size_t)u * 8)) =
          __builtin_shufflevector(lo, hi, 0, 1, 2, 3, 4, 5, 6, 7);
    }
    return;
  }
  int u = blockIdx.x * 256 + threadIdx.x;   // 786432 threads, one f16x8 each
  int g = u & 3;
  int ktp = (u >> 2) & 7;
  int q = (u >> 5) & 255;
  int grp = u >> 13;           // mg*6 + h
  int h = grp % 6;
  int mg = grp / 6;
  int k0 = ktp * 32 + g * 4;
  const int* rp = rpi + (q << 8) + k0;
  int4 i0 = *(const int4*)rp;
  int4 i1 = *(const int4*)(rp + 16);
  const float* mp = mask + ((size_t)mg << 16) + (q << 8) + k0;
  float4 mv0 = *(const float4*)mp;
  float4 mv1 = *(const float4*)(mp + 16);
  f16x2 a = pkrtz((rpb[i0.x * 6 + h] + mv0.x) * LOG2E,
                  (rpb[i0.y * 6 + h] + mv0.y) * LOG2E);
  f16x2 b = pkrtz((rpb[i0.z * 6 + h] + mv0.z) * LOG2E,
                  (rpb[i0.w * 6 + h] + mv0.w) * LOG2E);
  f16x2 c = pkrtz((rpb[i1.x * 6 + h] + mv1.x) * LOG2E,
                  (rpb[i1.y * 6 + h] + mv1.y) * LOG2E);
  f16x2 d = pkrtz((rpb[i1.z * 6 + h] + mv1.z) * LOG2E,
                  (rpb[i1.w * 6 + h] + mv1.w) * LOG2E);
  f16x4 lo = __builtin_shufflevector(a, b, 0, 1, 2, 3);
  f16x4 hi = __builtin_shufflevector(c, d, 0, 1, 2, 3);
  *((f16x8*)(cb + (size_t)u * 8)) =
      __builtin_shufflevector(lo, hi, 0, 1, 2, 3, 4, 5, 6, 7);
}

__device__ inline f16x8 q_to_f16(float4 a, float4 b) {
  f16x2 p0 = pkrtz(a.x * SCALE, a.y * SCALE);
  f16x2 p1 = pkrtz(a.z * SCALE, a.w * SCALE);
  f16x2 p2 = pkrtz(b.x * SCALE, b.y * SCALE);
  f16x2 p3 = pkrtz(b.z * SCALE, b.w * SCALE);
  f16x4 lo = __builtin_shufflevector(p0, p1, 0, 1, 2, 3);
  f16x4 hi = __builtin_shufflevector(p2, p3, 0, 1, 2, 3);
  return __builtin_shufflevector(lo, hi, 0, 1, 2, 3, 4, 5, 6, 7);
}

// ---------------------------------------------------------------------------
// Kernel 3: fused window attention — r14/r18 core (best known: 104.9 us).
// Persistent pairs, double-buffered staging (issue-early/write-late),
// f16 frag-major cb seeds MFMA C, XCD pinning (idx%96=grp), (512,4),
// max-based online softmax over 2 k-halves, PV dual chains.
// r15 (no-max), r16 (split bias), r19 (quads: reg spill + lost residency)
// all REGRESSED — this is the converged form.
// ---------------------------------------------------------------------------
__global__ __launch_bounds__(512, 4) void attn_kernel(const float* __restrict__ qkv,
                                                      const f16* __restrict__ cb,
                                                      f16* __restrict__ x16) {
  const int idx = blockIdx.x;
  const int grp = idx % 96;            // (b&15)*6 + h — pinned to XCD grp%8
  const int pr = idx / 96;             // 0..7
  const int h = grp % 6;
  const int blo = grp / 6;             // b & 15
  const int tid = threadIdx.x;
  const int lane = tid & 63;
  const int wave = tid >> 6;
  const int g = lane >> 4;
  const int r16 = lane & 15;

  __shared__ f16 Klin[2][16 * 64 * 8];
  __shared__ f16 VT[2][32][264];

  // staging role
  const int t = tid & 255;
  const int srow = t >> 3;
  const int part = t & 7;
  const bool isK = tid < 256;
  const int gg = part >> 1;
  const int half = part & 1;
  const int d0 = part * 4;

  const int b0 = ((pr * 2) << 4) | blo;
  const int b1 = ((pr * 2 + 1) << 4) | blo;
  const float* sbase0 = qkv + (size_t)(b0 * NTOK + srow) * C3 + DIM + (isK ? 0 : DIM)
                        + h * HD + part * 4;
  const float* sbase1 = qkv + (size_t)(b1 * NTOK + srow) * C3 + DIM + (isK ? 0 : DIM)
                        + h * HD + part * 4;

  auto stage_write = [&](int buf, int rgbase, const float4* v4) {
#pragma unroll
    for (int rg = 0; rg < 4; ++rg) {
      const int row = (rgbase + rg) * 32 + srow;
      if (isK) {
        const int slot = ((row >> 4) * 64) + gg * 16 + ((row & 15) ^ (gg << 2));
        f16x2 k01 = pkrtz(v4[rg].x, v4[rg].y);
        f16x2 k23 = pkrtz(v4[rg].z, v4[rg].w);
        *((f16x4*)&Klin[buf][slot * 8 + half * 4]) =
            __builtin_shufflevector(k01, k23, 0, 1, 2, 3);
      } else {
        VT[buf][d0 + 0][row ^ (((d0 + 0) & 7) << 2)] = (f16)v4[rg].x;
        VT[buf][d0 + 1][row ^ (((d0 + 1) & 7) << 2)] = (f16)v4[rg].y;
        VT[buf][d0 + 2][row ^ (((d0 + 2) & 7) << 2)] = (f16)v4[rg].z;
        VT[buf][d0 + 3][row ^ (((d0 + 3) & 7) << 2)] = (f16)v4[rg].w;
      }
    }
  };

  // ---- pair 0: full stage into buffer 0 ----
  {
    float4 s4[8];
#pragma unroll
    for (int i = 0; i < 8; ++i)
      s4[i] = *(const float4*)(sbase0 + (size_t)(i * 32) * C3);
    stage_write(0, 0, s4);
    stage_write(0, 4, s4 + 4);
  }
  __syncthreads();

  const f16* cbb = cb + ((size_t)grp << 16);
  const int krd = (lane & 48) + ((lane & 15) ^ ((lane >> 2) & 12));
  const int qbase = wave * 32;

#pragma unroll
  for (int pair = 0; pair < 2; ++pair) {
    const int b = (pair == 0) ? b0 : b1;

#pragma unroll
    for (int c = 0; c < 2; ++c) {
      // issue next pair's staging loads (batch c)
      float4 n4[4];
      if (pair == 0) {
#pragma unroll
        for (int i = 0; i < 4; ++i)
          n4[i] = *(const float4*)(sbase1 + (size_t)((c * 4 + i) * 32) * C3);
      }

      const int qrow = qbase + c * 16 + r16;
      const float* qp = qkv + (size_t)(b * NTOK + qrow) * C3 + h * HD + g * 8;
      f16x8 qf = q_to_f16(((const float4*)qp)[0], ((const float4*)qp)[1]);
      const f16* cbq = cbb + (qrow << 8) + g * 8;

      // ================= phase A: keys 0..127 =================
      f16x8 cv[4];
#pragma unroll
      for (int kp = 0; kp < 4; ++kp) cv[kp] = *((const f16x8*)(cbq + kp * 32));
      f32x4 acc[8];
#pragma unroll
      for (int kp = 0; kp < 4; ++kp) {
#pragma unroll
        for (int r = 0; r < 4; ++r) {
          acc[2 * kp][r] = (float)cv[kp][r];
          acc[2 * kp + 1][r] = (float)cv[kp][4 + r];
        }
      }
#pragma unroll
      for (int kt = 0; kt < 8; ++kt) {
        f16x8 af = *((const f16x8*)&Klin[pair][(kt * 64 + krd) * 8]);
        acc[kt] = __builtin_amdgcn_mfma_f32_16x16x32_f16(af, qf, acc[kt], 0, 0, 0);
      }

      // write next pair's staging batch (loads have had QK latency to land)
      if (pair == 0) stage_write(1, c * 4, n4);

      float m0 = fmaxf(fmaxf(acc[0][0], acc[1][0]), fmaxf(acc[2][0], acc[3][0]));
      float m1 = fmaxf(fmaxf(acc[0][1], acc[1][1]), fmaxf(acc[2][1], acc[3][1]));
      float m2 = fmaxf(fmaxf(acc[0][2], acc[1][2]), fmaxf(acc[2][2], acc[3][2]));
      float m3 = fmaxf(fmaxf(acc[0][3], acc[1][3]), fmaxf(acc[2][3], acc[3][3]));
#pragma unroll
      for (int kt = 4; kt < 8; ++kt) {
        m0 = fmaxf(m0, acc[kt][0]); m1 = fmaxf(m1, acc[kt][1]);
        m2 = fmaxf(m2, acc[kt][2]); m3 = fmaxf(m3, acc[kt][3]);
      }
      float mA = fmaxf(fmaxf(m0, m1), fmaxf(m2, m3));
      mA = fmaxf(mA, __shfl_xor(mA, 16));
      mA = fmaxf(mA, __shfl_xor(mA, 32));

      float s0 = 0.f, s1 = 0.f, s2 = 0.f, s3 = 0.f;
#pragma unroll
      for (int kt = 0; kt < 8; ++kt) {
        float p0 = __builtin_amdgcn_exp2f(acc[kt][0] - mA);
        float p1 = __builtin_amdgcn_exp2f(acc[kt][1] - mA);
        float p2 = __builtin_amdgcn_exp2f(acc[kt][2] - mA);
        float p3 = __builtin_amdgcn_exp2f(acc[kt][3] - mA);
        acc[kt][0] = p0; acc[kt][1] = p1; acc[kt][2] = p2; acc[kt][3] = p3;
        s0 += p0; s1 += p1; s2 += p2; s3 += p3;
      }
      float sA = (s0 + s1) + (s2 + s3);

      // PV phase A — 2 chains per dt
      f32x4 xa0[2], xa1[2];
#pragma unroll
      for (int dt = 0; dt < 2; ++dt) {
        xa0[dt][0] = 0.f; xa0[dt][1] = 0.f; xa0[dt][2] = 0.f; xa0[dt][3] = 0.f;
        xa1[dt][0] = 0.f; xa1[dt][1] = 0.f; xa1[dt][2] = 0.f; xa1[dt][3] = 0.f;
      }
#pragma unroll
      for (int kt = 0; kt < 8; ++kt) {
        f16x2 p01 = pkrtz(acc[kt][0], acc[kt][1]);
        f16x2 p23 = pkrtz(acc[kt][2], acc[kt][3]);
        f16x4 pf = __builtin_shufflevector(p01, p23, 0, 1, 2, 3);
#pragma unroll
        for (int dt = 0; dt < 2; ++dt) {
          const int col = (kt * 16 + g * 4) ^ ((r16 & 7) << 2);
          f16x4 vf = *((const f16x4*)&VT[pair][dt * 16 + r16][col]);
          if (kt < 4)
            xa0[dt] = __builtin_amdgcn_mfma_f32_16x16x16f16(vf, pf, xa0[dt], 0, 0, 0);
          else
            xa1[dt] = __builtin_amdgcn_mfma_f32_16x16x16f16(vf, pf, xa1[dt], 0, 0, 0);
        }
      }

      // ================= phase B: keys 128..255 =================
#pragma unroll
      for (int kp = 0; kp < 4; ++kp) cv[kp] = *((const f16x8*)(cbq + 128 + kp * 32));
#pragma unroll
      for (int kp = 0; kp < 4; ++kp) {
#pragma unroll
        for (int r = 0; r < 4; ++r) {
          acc[2 * kp][r] = (float)cv[kp][r];
          acc[2 * kp + 1][r] = (float)cv[kp][4 + r];
        }
      }
#pragma unroll
      for (int kt = 0; kt < 8; ++kt) {
        f16x8 af = *((const f16x8*)&Klin[pair][((kt + 8) * 64 + krd) * 8]);
        acc[kt] = __builtin_amdgcn_mfma_f32_16x16x32_f16(af, qf, acc[kt], 0, 0, 0);
      }

      m0 = fmaxf(fmaxf(acc[0][0], acc[1][0]), fmaxf(acc[2][0], acc[3][0]));
      m1 = fmaxf(fmaxf(acc[0][1], acc[1][1]), fmaxf(acc[2][1], acc[3][1]));
      m2 = fmaxf(fmaxf(acc[0][2], acc[1][2]), fmaxf(acc[2][2], acc[3][2]));
      m3 = fmaxf(fmaxf(acc[0][3], acc[1][3]), fmaxf(acc[2][3], acc[3][3]));
#pragma unroll
      for (int kt = 4; kt < 8; ++kt) {
        m0 = fmaxf(m0, acc[kt][0]); m1 = fmaxf(m1, acc[kt][1]);
        m2 = fmaxf(m2, acc[kt][2]); m3 = fmaxf(m3, acc[kt][3]);
      }
      float mB = fmaxf(fmaxf(m0, m1), fmaxf(m2, m3));
      mB = fmaxf(mB, __shfl_xor(mB, 16));
      mB = fmaxf(mB, __shfl_xor(mB, 32));

      const float m = fmaxf(mA, mB);
      const float scA = __builtin_amdgcn_exp2f(mA - m);

      s0 = 0.f; s1 = 0.f; s2 = 0.f; s3 = 0.f;
#pragma unroll
      for (int kt = 0; kt < 8; ++kt) {
        float p0 = __builtin_amdgcn_exp2f(acc[kt][0] - m);
        float p1 = __builtin_amdgcn_exp2f(acc[kt][1] - m);
        float p2 = __builtin_amdgcn_exp2f(acc[kt][2] - m);
        float p3 = __builtin_amdgcn_exp2f(acc[kt][3] - m);
        acc[kt][0] = p0; acc[kt][1] = p1; acc[kt][2] = p2; acc[kt][3] = p3;
        s0 += p0; s1 += p1; s2 += p2; s3 += p3;
      }
      float s = sA * scA + (s0 + s1) + (s2 + s3);
      s += __shfl_xor(s, 16);
      s += __shfl_xor(s, 32);
      const float rinv = 1.0f / s;

#pragma unroll
      for (int dt = 0; dt < 2; ++dt) {
        xa0[dt][0] *= scA; xa0[dt][1] *= scA; xa0[dt][2] *= scA; xa0[dt][3] *= scA;
        xa1[dt][0] *= scA; xa1[dt][1] *= scA; xa1[dt][2] *= scA; xa1[dt][3] *= scA;
      }
#pragma unroll
      for (int kt = 0; kt < 8; ++kt) {
        f16x2 p01 = pkrtz(acc[kt][0], acc[kt][1]);
        f16x2 p23 = pkrtz(acc[kt][2], acc[kt][3]);
        f16x4 pf = __builtin_shufflevector(p01, p23, 0, 1, 2, 3);
#pragma unroll
        for (int dt = 0; dt < 2; ++dt) {
          const int col = ((kt + 8) * 16 + g * 4) ^ ((r16 & 7) << 2);
          f16x4 vf = *((const f16x4*)&VT[pair][dt * 16 + r16][col]);
          if (kt < 4)
            xa0[dt] = __builtin_amdgcn_mfma_f32_16x16x16f16(vf, pf, xa0[dt], 0, 0, 0);
          else
            xa1[dt] = __builtin_amdgcn_mfma_f32_16x16x16f16(vf, pf, xa1[dt], 0, 0, 0);
        }
      }

      // write x (f16) [b][token][192], normalized
      f16* xp = x16 + (size_t)(b * NTOK + qrow) * DIM + h * HD;
#pragma unroll
      for (int dt = 0; dt < 2; ++dt) {
        f16x2 o01 = pkrtz((xa0[dt][0] + xa1[dt][0]) * rinv,
                          (xa0[dt][1] + xa1[dt][1]) * rinv);
        f16x2 o23 = pkrtz((xa0[dt][2] + xa1[dt][2]) * rinv,
                          (xa0[dt][3] + xa1[dt][3]) * rinv);
        *((f16x4*)(xp + dt * 16 + g * 4)) = __builtin_shufflevector(o01, o23, 0, 1, 2, 3);
      }
    }

    // pair boundary: buf1 staging writes must be visible before pair1 reads
    if (pair == 0) __syncthreads();
  }
}

// ---------------------------------------------------------------------------
// Kernel 4: out = X16 @ W16^T + pb
// ---------------------------------------------------------------------------
__global__ __launch_bounds__(256) void proj_kernel(const f16* __restrict__ x16,
                                                   const f16* __restrict__ w16,
                                                   const float* __restrict__ pb,
                                                   float* __restrict__ out) {
  const int lane = threadIdx.x & 63;
  const int wave = threadIdx.x >> 6;
  const int g = lane >> 4;
  const int r16 = lane & 15;
  const int m0 = blockIdx.x * 64 + wave * 16;

  f32x4 acc[12];
#pragma unroll
  for (int jt = 0; jt < 12; ++jt) {
    acc[jt][0] = 0.f; acc[jt][1] = 0.f; acc[jt][2] = 0.f; acc[jt][3] = 0.f;
  }
#pragma unroll
  for (int cc = 0; cc < 6; ++cc) {
    f16x8 af = *((const f16x8*)(x16 + (size_t)(m0 + r16) * DIM + cc * 32 + g * 8));
#pragma unroll
    for (int jt = 0; jt < 12; ++jt) {
      f16x8 bf = *((const f16x8*)(w16 + (size_t)(jt * 16 + r16) * DIM + cc * 32 + g * 8));
      acc[jt] = __builtin_amdgcn_mfma_f32_16x16x32_f16(af, bf, acc[jt], 0, 0, 0);
    }
  }
#pragma unroll
  for (int jt = 0; jt < 12; ++jt) {
    int j = jt * 16 + r16;
    float bias = pb[j];
#pragma unroll
    for (int r = 0; r < 4; ++r) {
      out[(size_t)(m0 + g * 4 + r) * DIM + j] = acc[jt][r] + bias;
    }
  }
}

// ---------------------------------------------------------------------------
extern "C" void kernel_launch(void* const* d_in, const int* in_sizes, int n_in,
                              void* d_out, int out_size, void* d_ws, size_t ws_size,
                              hipStream_t stream) {
  const float* qkv  = (const float*)d_in[0];
  const int*   rpi  = (const int*)d_in[1];
  const float* mask = (const float*)d_in[2];
  const float* rpb  = (const float*)d_in[3];
  const float* pw   = (const float*)d_in[4];
  const float* pbv  = (const float*)d_in[5];
  float* out = (float*)d_out;

  char* ws = (char*)d_ws;
  f16* cb16 = (f16*)ws;                              // 12,582,912 B
  f16* x16  = (f16*)(ws + 12582912);                 // 25,165,824 B
  f16* w16  = (f16*)(ws + 12582912 + 25165824);      // 73,728 B

  prep_kernel<<<3090, 256, 0, stream>>>(rpi, mask, rpb, pw, cb16, w16);
  attn_kernel<<<768, 512, 0, stream>>>(qkv, cb16, x16);
  proj_kernel<<<1024, 256, 0, stream>>>(x16, w16, pbv, out);
}

// Round 21
// 104.183 us; speedup vs baseline: 1.2447x; 1.0342x over previous
//
#include <hip/hip_runtime.h>
#include <hip/hip_bf16.h>

typedef _Float16 f16;
typedef _Float16 f16x2 __attribute__((ext_vector_type(2)));
typedef _Float16 f16x4 __attribute__((ext_vector_type(4)));
typedef _Float16 f16x8 __attribute__((ext_vector_type(8)));
typedef __fp16 h16x2 __attribute__((ext_vector_type(2)));
typedef float f32x4 __attribute__((ext_vector_type(4)));

// Problem constants
#define NHEADS 6
#define NTOK 256
#define NWINS 256
#define DIM 192
#define HD 32
#define C3 576
#define LOG2E 1.4426950408889634f
#define SCALE (0.17677669529663687f * LOG2E)

__device__ inline f16x2 pkrtz(float a, float b) {
  h16x2 r = __builtin_amdgcn_cvt_pkrtz(a, b);
  return __builtin_bit_cast(f16x2, r);
}

// ---------------------------------------------------------------------------
// Kernel 1 (fused prep): blocks [0,3072) build cb16 (frag-major, vectorized);
// blocks [3072, 3090) convert W fp32->f16 (36864 elems, f16x8 each).
//   cb16[grp][q][ktp][g][e], grp = mg*6+h; element (q,k),
//   k = (2*ktp + (e>>2))*16 + g*4 + (e&3)
// ---------------------------------------------------------------------------
__global__ __launch_bounds__(256) void prep_kernel(const int* __restrict__ rpi,
                                                   const float* __restrict__ mask,
                                                   const float* __restrict__ rpb,
                                                   const float* __restrict__ w,
                                                   f16* __restrict__ cb,
                                                   f16* __restrict__ w16) {
  if (blockIdx.x >= 3072) {
    int u = (blockIdx.x - 3072) * 256 + threadIdx.x;
    if (u < 4608) {
      const float* wp = w + u * 8;
      float4 v0 = *(const float4*)wp;
      float4 v1 = *(const float4*)(wp + 4);
      f16x2 a = pkrtz(v0.x, v0.y);
      f16x2 b = pkrtz(v0.z, v0.w);
      f16x2 c = pkrtz(v1.x, v1.y);
      f16x2 d = pkrtz(v1.z, v1.w);
      f16x4 lo = __builtin_shufflevector(a, b, 0, 1, 2, 3);
      f16x4 hi = __builtin_shufflevector(c, d, 0, 1, 2, 3);
      *((f16x8*)(w16 + (size_t)u * 8)) =
          __builtin_shufflevector(lo, hi, 0, 1, 2, 3, 4, 5, 6, 7);
    }
    return;
  }
  int u = blockIdx.x * 256 + threadIdx.x;   // 786432 threads, one f16x8 each
  int g = u & 3;
  int ktp = (u >> 2) & 7;
  int q = (u >> 5) & 255;
  int grp = u >> 13;           // mg*6 + h
  int h = grp % 6;
  int mg = grp / 6;
  int k0 = ktp * 32 + g * 4;
  const int* rp = rpi + (q << 8) + k0;
  int4 i0 = *(const int4*)rp;
  int4 i1 = *(const int4*)(rp + 16);
  const float* mp = mask + ((size_t)mg << 16) + (q << 8) + k0;
  float4 mv0 = *(const float4*)mp;
  float4 mv1 = *(const float4*)(mp + 16);
  f16x2 a = pkrtz((rpb[i0.x * 6 + h] + mv0.x) * LOG2E,
                  (rpb[i0.y * 6 + h] + mv0.y) * LOG2E);
  f16x2 b = pkrtz((rpb[i0.z * 6 + h] + mv0.z) * LOG2E,
                  (rpb[i0.w * 6 + h] + mv0.w) * LOG2E);
  f16x2 c = pkrtz((rpb[i1.x * 6 + h] + mv1.x) * LOG2E,
                  (rpb[i1.y * 6 + h] + mv1.y) * LOG2E);
  f16x2 d = pkrtz((rpb[i1.z * 6 + h] + mv1.z) * LOG2E,
                  (rpb[i1.w * 6 + h] + mv1.w) * LOG2E);
  f16x4 lo = __builtin_shufflevector(a, b, 0, 1, 2, 3);
  f16x4 hi = __builtin_shufflevector(c, d, 0, 1, 2, 3);
  *((f16x8*)(cb + (size_t)u * 8)) =
      __builtin_shufflevector(lo, hi, 0, 1, 2, 3, 4, 5, 6, 7);
}

__device__ inline f16x8 q_to_f16(float4 a, float4 b) {
  f16x2 p0 = pkrtz(a.x * SCALE, a.y * SCALE);
  f16x2 p1 = pkrtz(a.z * SCALE, a.w * SCALE);
  f16x2 p2 = pkrtz(b.x * SCALE, b.y * SCALE);
  f16x2 p3 = pkrtz(b.z * SCALE, b.w * SCALE);
  f16x4 lo = __builtin_shufflevector(p0, p1, 0, 1, 2, 3);
  f16x4 hi = __builtin_shufflevector(p2, p3, 0, 1, 2, 3);
  return __builtin_shufflevector(lo, hi, 0, 1, 2, 3, 4, 5, 6, 7);
}

// ---------------------------------------------------------------------------
// Kernel 3: fused window attention — r18 core + T5 s_setprio around MFMA
// clusters (r21). Waves within a pair run chunks independently (no barrier)
// -> phase diversity -> setprio(1) biases the CU scheduler toward waves in
// their MFMA cluster while others issue memory ops (learn_hip m191: +4-7%
// on attn with phase-diverse waves; NULL only on lockstep schedules).
// Else byte-identical to r18: persistent pairs, double-buffered staging,
// f16 frag-major cb seeds MFMA C, XCD pinning, (512,4), online softmax.
// ---------------------------------------------------------------------------
__global__ __launch_bounds__(512, 4) void attn_kernel(const float* __restrict__ qkv,
                                                      const f16* __restrict__ cb,
                                                      f16* __restrict__ x16) {
  const int idx = blockIdx.x;
  const int grp = idx % 96;            // (b&15)*6 + h — pinned to XCD grp%8
  const int pr = idx / 96;             // 0..7
  const int h = grp % 6;
  const int blo = grp / 6;             // b & 15
  const int tid = threadIdx.x;
  const int lane = tid & 63;
  const int wave = tid >> 6;
  const int g = lane >> 4;
  const int r16 = lane & 15;

  __shared__ f16 Klin[2][16 * 64 * 8];
  __shared__ f16 VT[2][32][264];

  // staging role
  const int t = tid & 255;
  const int srow = t >> 3;
  const int part = t & 7;
  const bool isK = tid < 256;
  const int gg = part >> 1;
  const int half = part & 1;
  const int d0 = part * 4;

  const int b0 = ((pr * 2) << 4) | blo;
  const int b1 = ((pr * 2 + 1) << 4) | blo;
  const float* sbase0 = qkv + (size_t)(b0 * NTOK + srow) * C3 + DIM + (isK ? 0 : DIM)
                        + h * HD + part * 4;
  const float* sbase1 = qkv + (size_t)(b1 * NTOK + srow) * C3 + DIM + (isK ? 0 : DIM)
                        + h * HD + part * 4;

  auto stage_write = [&](int buf, int rgbase, const float4* v4) {
#pragma unroll
    for (int rg = 0; rg < 4; ++rg) {
      const int row = (rgbase + rg) * 32 + srow;
      if (isK) {
        const int slot = ((row >> 4) * 64) + gg * 16 + ((row & 15) ^ (gg << 2));
        f16x2 k01 = pkrtz(v4[rg].x, v4[rg].y);
        f16x2 k23 = pkrtz(v4[rg].z, v4[rg].w);
        *((f16x4*)&Klin[buf][slot * 8 + half * 4]) =
            __builtin_shufflevector(k01, k23, 0, 1, 2, 3);
      } else {
        VT[buf][d0 + 0][row ^ (((d0 + 0) & 7) << 2)] = (f16)v4[rg].x;
        VT[buf][d0 + 1][row ^ (((d0 + 1) & 7) << 2)] = (f16)v4[rg].y;
        VT[buf][d0 + 2][row ^ (((d0 + 2) & 7) << 2)] = (f16)v4[rg].z;
        VT[buf][d0 + 3][row ^ (((d0 + 3) & 7) << 2)] = (f16)v4[rg].w;
      }
    }
  };

  // ---- pair 0: full stage into buffer 0 ----
  {
    float4 s4[8];
#pragma unroll
    for (int i = 0; i < 8; ++i)
      s4[i] = *(const float4*)(sbase0 + (size_t)(i * 32) * C3);
    stage_write(0, 0, s4);
    stage_write(0, 4, s4 + 4);
  }
  __syncthreads();

  const f16* cbb = cb + ((size_t)grp << 16);
  const int krd = (lane & 48) + ((lane & 15) ^ ((lane >> 2) & 12));
  const int qbase = wave * 32;

#pragma unroll
  for (int pair = 0; pair < 2; ++pair) {
    const int b = (pair == 0) ? b0 : b1;

#pragma unroll
    for (int c = 0; c < 2; ++c) {
      // issue next pair's staging loads (batch c)
      float4 n4[4];
      if (pair == 0) {
#pragma unroll
        for (int i = 0; i < 4; ++i)
          n4[i] = *(const float4*)(sbase1 + (size_t)((c * 4 + i) * 32) * C3);
      }

      const int qrow = qbase + c * 16 + r16;
      const float* qp = qkv + (size_t)(b * NTOK + qrow) * C3 + h * HD + g * 8;
      f16x8 qf = q_to_f16(((const float4*)qp)[0], ((const float4*)qp)[1]);
      const f16* cbq = cbb + (qrow << 8) + g * 8;

      // ================= phase A: keys 0..127 =================
      f16x8 cv[4];
#pragma unroll
      for (int kp = 0; kp < 4; ++kp) cv[kp] = *((const f16x8*)(cbq + kp * 32));
      f32x4 acc[8];
#pragma unroll
      for (int kp = 0; kp < 4; ++kp) {
#pragma unroll
        for (int r = 0; r < 4; ++r) {
          acc[2 * kp][r] = (float)cv[kp][r];
          acc[2 * kp + 1][r] = (float)cv[kp][4 + r];
        }
      }
      __builtin_amdgcn_s_setprio(1);
#pragma unroll
      for (int kt = 0; kt < 8; ++kt) {
        f16x8 af = *((const f16x8*)&Klin[pair][(kt * 64 + krd) * 8]);
        acc[kt] = __builtin_amdgcn_mfma_f32_16x16x32_f16(af, qf, acc[kt], 0, 0, 0);
      }
      __builtin_amdgcn_s_setprio(0);

      // write next pair's staging batch (loads have had QK latency to land)
      if (pair == 0) stage_write(1, c * 4, n4);

      float m0 = fmaxf(fmaxf(acc[0][0], acc[1][0]), fmaxf(acc[2][0], acc[3][0]));
      float m1 = fmaxf(fmaxf(acc[0][1], acc[1][1]), fmaxf(acc[2][1], acc[3][1]));
      float m2 = fmaxf(fmaxf(acc[0][2], acc[1][2]), fmaxf(acc[2][2], acc[3][2]));
      float m3 = fmaxf(fmaxf(acc[0][3], acc[1][3]), fmaxf(acc[2][3], acc[3][3]));
#pragma unroll
      for (int kt = 4; kt < 8; ++kt) {
        m0 = fmaxf(m0, acc[kt][0]); m1 = fmaxf(m1, acc[kt][1]);
        m2 = fmaxf(m2, acc[kt][2]); m3 = fmaxf(m3, acc[kt][3]);
      }
      float mA = fmaxf(fmaxf(m0, m1), fmaxf(m2, m3));
      mA = fmaxf(mA, __shfl_xor(mA, 16));
      mA = fmaxf(mA, __shfl_xor(mA, 32));

      float s0 = 0.f, s1 = 0.f, s2 = 0.f, s3 = 0.f;
#pragma unroll
      for (int kt = 0; kt < 8; ++kt) {
        float p0 = __builtin_amdgcn_exp2f(acc[kt][0] - mA);
        float p1 = __builtin_amdgcn_exp2f(acc[kt][1] - mA);
        float p2 = __builtin_amdgcn_exp2f(acc[kt][2] - mA);
        float p3 = __builtin_amdgcn_exp2f(acc[kt][3] - mA);
        acc[kt][0] = p0; acc[kt][1] = p1; acc[kt][2] = p2; acc[kt][3] = p3;
        s0 += p0; s1 += p1; s2 += p2; s3 += p3;
      }
      float sA = (s0 + s1) + (s2 + s3);

      // PV phase A — 2 chains per dt
      f32x4 xa0[2], xa1[2];
#pragma unroll
      for (int dt = 0; dt < 2; ++dt) {
        xa0[dt][0] = 0.f; xa0[dt][1] = 0.f; xa0[dt][2] = 0.f; xa0[dt][3] = 0.f;
        xa1[dt][0] = 0.f; xa1[dt][1] = 0.f; xa1[dt][2] = 0.f; xa1[dt][3] = 0.f;
      }
      __builtin_amdgcn_s_setprio(1);
#pragma unroll
      for (int kt = 0; kt < 8; ++kt) {
        f16x2 p01 = pkrtz(acc[kt][0], acc[kt][1]);
        f16x2 p23 = pkrtz(acc[kt][2], acc[kt][3]);
        f16x4 pf = __builtin_shufflevector(p01, p23, 0, 1, 2, 3);
#pragma unroll
        for (int dt = 0; dt < 2; ++dt) {
          const int col = (kt * 16 + g * 4) ^ ((r16 & 7) << 2);
          f16x4 vf = *((const f16x4*)&VT[pair][dt * 16 + r16][col]);
          if (kt < 4)
            xa0[dt] = __builtin_amdgcn_mfma_f32_16x16x16f16(vf, pf, xa0[dt], 0, 0, 0);
          else
            xa1[dt] = __builtin_amdgcn_mfma_f32_16x16x16f16(vf, pf, xa1[dt], 0, 0, 0);
        }
      }
      __builtin_amdgcn_s_setprio(0);

      // ================= phase B: keys 128..255 =================
#pragma unroll
      for (int kp = 0; kp < 4; ++kp) cv[kp] = *((const f16x8*)(cbq + 128 + kp * 32));
#pragma unroll
      for (int kp = 0; kp < 4; ++kp) {
#pragma unroll
        for (int r = 0; r < 4; ++r) {
          acc[2 * kp][r] = (float)cv[kp][r];
          acc[2 * kp + 1][r] = (float)cv[kp][4 + r];
        }
      }
      __builtin_amdgcn_s_setprio(1);
#pragma unroll
      for (int kt = 0; kt < 8; ++kt) {
        f16x8 af = *((const f16x8*)&Klin[pair][((kt + 8) * 64 + krd) * 8]);
        acc[kt] = __builtin_amdgcn_mfma_f32_16x16x32_f16(af, qf, acc[kt], 0, 0, 0);
      }
      __builtin_amdgcn_s_setprio(0);

      m0 = fmaxf(fmaxf(acc[0][0], acc[1][0]), fmaxf(acc[2][0], acc[3][0]));
      m1 = fmaxf(fmaxf(acc[0][1], acc[1][1]), fmaxf(acc[2][1], acc[3][1]));
      m2 = fmaxf(fmaxf(acc[0][2], acc[1][2]), fmaxf(acc[2][2], acc[3][2]));
      m3 = fmaxf(fmaxf(acc[0][3], acc[1][3]), fmaxf(acc[2][3], acc[3][3]));
#pragma unroll
      for (int kt = 4; kt < 8; ++kt) {
        m0 = fmaxf(m0, acc[kt][0]); m1 = fmaxf(m1, acc[kt][1]);
        m2 = fmaxf(m2, acc[kt][2]); m3 = fmaxf(m3, acc[kt][3]);
      }
      float mB = fmaxf(fmaxf(m0, m1), fmaxf(m2, m3));
      mB = fmaxf(mB, __shfl_xor(mB, 16));
      mB = fmaxf(mB, __shfl_xor(mB, 32));

      const float m = fmaxf(mA, mB);
      const float scA = __builtin_amdgcn_exp2f(mA - m);

      s0 = 0.f; s1 = 0.f; s2 = 0.f; s3 = 0.f;
#pragma unroll
      for (int kt = 0; kt < 8; ++kt) {
        float p0 = __builtin_amdgcn_exp2f(acc[kt][0] - m);
        float p1 = __builtin_amdgcn_exp2f(acc[kt][1] - m);
        float p2 = __builtin_amdgcn_exp2f(acc[kt][2] - m);
        float p3 = __builtin_amdgcn_exp2f(acc[kt][3] - m);
        acc[kt][0] = p0; acc[kt][1] = p1; acc[kt][2] = p2; acc[kt][3] = p3;
        s0 += p0; s1 += p1; s2 += p2; s3 += p3;
      }
      float s = sA * scA + (s0 + s1) + (s2 + s3);
      s += __shfl_xor(s, 16);
      s += __shfl_xor(s, 32);
      const float rinv = 1.0f / s;

#pragma unroll
      for (int dt = 0; dt < 2; ++dt) {
        xa0[dt][0] *= scA; xa0[dt][1] *= scA; xa0[dt][2] *= scA; xa0[dt][3] *= scA;
        xa1[dt][0] *= scA; xa1[dt][1] *= scA; xa1[dt][2] *= scA; xa1[dt][3] *= scA;
      }
      __builtin_amdgcn_s_setprio(1);
#pragma unroll
      for (int kt = 0; kt < 8; ++kt) {
        f16x2 p01 = pkrtz(acc[kt][0], acc[kt][1]);
        f16x2 p23 = pkrtz(acc[kt][2], acc[kt][3]);
        f16x4 pf = __builtin_shufflevector(p01, p23, 0, 1, 2, 3);
#pragma unroll
        for (int dt = 0; dt < 2; ++dt) {
          const int col = ((kt + 8) * 16 + g * 4) ^ ((r16 & 7) << 2);
          f16x4 vf = *((const f16x4*)&VT[pair][dt * 16 + r16][col]);
          if (kt < 4)
            xa0[dt] = __builtin_amdgcn_mfma_f32_16x16x16f16(vf, pf, xa0[dt], 0, 0, 0);
          else
            xa1[dt] = __builtin_amdgcn_mfma_f32_16x16x16f16(vf, pf, xa1[dt], 0, 0, 0);
        }
      }
      __builtin_amdgcn_s_setprio(0);

      // write x (f16) [b][token][192], normalized
      f16* xp = x16 + (size_t)(b * NTOK + qrow) * DIM + h * HD;
#pragma unroll
      for (int dt = 0; dt < 2; ++dt) {
        f16x2 o01 = pkrtz((xa0[dt][0] + xa1[dt][0]) * rinv,
                          (xa0[dt][1] + xa1[dt][1]) * rinv);
        f16x2 o23 = pkrtz((xa0[dt][2] + xa1[dt][2]) * rinv,
                          (xa0[dt][3] + xa1[dt][3]) * rinv);
        *((f16x4*)(xp + dt * 16 + g * 4)) = __builtin_shufflevector(o01, o23, 0, 1, 2, 3);
      }
    }

    // pair boundary: buf1 staging writes must be visible before pair1 reads
    if (pair == 0) __syncthreads();
  }
}

// ---------------------------------------------------------------------------
// Kernel 4: out = X16 @ W16^T + pb
// ---------------------------------------------------------------------------
__global__ __launch_bounds__(256) void proj_kernel(const f16* __restrict__ x16,
                                                   const f16* __restrict__ w16,
                                                   const float* __restrict__ pb,
                                                   float* __restrict__ out) {
  const int lane = threadIdx.x & 63;
  const int wave = threadIdx.x >> 6;
  const int g = lane >> 4;
  const int r16 = lane & 15;
  const int m0 = blockIdx.x * 64 + wave * 16;

  f32x4 acc[12];
#pragma unroll
  for (int jt = 0; jt < 12; ++jt) {
    acc[jt][0] = 0.f; acc[jt][1] = 0.f; acc[jt][2] = 0.f; acc[jt][3] = 0.f;
  }
#pragma unroll
  for (int cc = 0; cc < 6; ++cc) {
    f16x8 af = *((const f16x8*)(x16 + (size_t)(m0 + r16) * DIM + cc * 32 + g * 8));
#pragma unroll
    for (int jt = 0; jt < 12; ++jt) {
      f16x8 bf = *((const f16x8*)(w16 + (size_t)(jt * 16 + r16) * DIM + cc * 32 + g * 8));
      acc[jt] = __builtin_amdgcn_mfma_f32_16x16x32_f16(af, bf, acc[jt], 0, 0, 0);
    }
  }
#pragma unroll
  for (int jt = 0; jt < 12; ++jt) {
    int j = jt * 16 + r16;
    float bias = pb[j];
#pragma unroll
    for (int r = 0; r < 4; ++r) {
      out[(size_t)(m0 + g * 4 + r) * DIM + j] = acc[jt][r] + bias;
    }
  }
}

// ---------------------------------------------------------------------------
extern "C" void kernel_launch(void* const* d_in, const int* in_sizes, int n_in,
                              void* d_out, int out_size, void* d_ws, size_t ws_size,
                              hipStream_t stream) {
  const float* qkv  = (const float*)d_in[0];
  const int*   rpi  = (const int*)d_in[1];
  const float* mask = (const float*)d_in[2];
  const float* rpb  = (const float*)d_in[3];
  const float* pw   = (const float*)d_in[4];
  const float* pbv  = (const float*)d_in[5];
  float* out = (float*)d_out;

  char* ws = (char*)d_ws;
  f16* cb16 = (f16*)ws;                              // 12,582,912 B
  f16* x16  = (f16*)(ws + 12582912);                 // 25,165,824 B
  f16* w16  = (f16*)(ws + 12582912 + 25165824);      // 73,728 B

  prep_kernel<<<3090, 256, 0, stream>>>(rpi, mask, rpb, pw, cb16, w16);
  attn_kernel<<<768, 512, 0, stream>>>(qkv, cb16, x16);
  proj_kernel<<<1024, 256, 0, stream>>>(x16, w16, pbv, out);
}